// Round 1
// baseline (1206.002 us; speedup 1.0000x reference)
//
#include <hip/hip_runtime.h>
#include <math.h>

// Problem constants (from reference setup_inputs)
#define NN 200000
#define FD 512
#define LD 40
#define HD 256
#define SGN 512
#define HID1 128
#define HID2 512
#define GD (2*FD + 3*LD)   // 1144

// Fused kernel:
//   block 0            : full serial MLP chain + gumbel_topk + writes inj rows
//   blocks 1..grid-1   : float4 grid-stride copy feat -> out rows [0,N)
__global__ __launch_bounds__(512) void attrgen_fused(
    const int*   __restrict__ target,
    const int*   __restrict__ sub_nodes,
    const float* __restrict__ feat,
    const float* __restrict__ node_emb,
    const float* __restrict__ wlabel,
    const float* __restrict__ wsec,
    const float* __restrict__ weight1,
    const float* __restrict__ weight2,
    const float* __restrict__ W1,
    const float* __restrict__ b1,
    const float* __restrict__ W2,
    const float* __restrict__ b2,
    const float* __restrict__ W3,
    const float* __restrict__ b3,
    const int*   __restrict__ feat_num,
    float*       __restrict__ out)
{
    const int tid = threadIdx.x;

    if (blockIdx.x != 0) {
        // ---- bulk copy path: new_feat[0:N] = feat ----
        const float4* __restrict__ src = (const float4*)feat;
        float4*       __restrict__ dst = (float4*)out;
        const size_t total4 = (size_t)NN * FD / 4;            // 25,600,000
        size_t i = (size_t)(blockIdx.x - 1) * blockDim.x + tid;
        const size_t stride = (size_t)(gridDim.x - 1) * blockDim.x;
        for (; i < total4; i += stride) dst[i] = src[i];
        return;
    }

    // ---------------- block 0: scalar compute chain ----------------
    __shared__ int   s_idx[SGN];
    __shared__ float s_featT[FD];
    __shared__ float s_graph[GD];
    __shared__ float s_tmp[HD];
    __shared__ float s_h1[HID1];
    __shared__ float s_h2[HID2];
    __shared__ float s_mask[FD];
    __shared__ float s_redV[8];
    __shared__ int   s_redI[8];
    __shared__ float s_bcastV;
    __shared__ int   s_bcastI;

    const int tgt = target[0];
    s_idx[tid] = sub_nodes[tid];
    __syncthreads();

    // sub_graph_emb (mean over 512 gathered rows) -> graph[0:512]
    // node_emb[target] -> graph[512:1024]; feat[target] staged
    {
        double acc = 0.0;
        #pragma unroll 8
        for (int n = 0; n < SGN; ++n)
            acc += (double)node_emb[(size_t)s_idx[n] * FD + tid];
        s_graph[tid]      = (float)(acc * (1.0 / (double)SGN));
        s_graph[FD + tid] = node_emb[(size_t)tgt * FD + tid];
        s_featT[tid]      = feat[(size_t)tgt * FD + tid];
    }
    __syncthreads();

    // tmp_emb = relu(feat[target] @ weight1)   [256]
    if (tid < HD) {
        double acc = 0.0;
        #pragma unroll 4
        for (int k = 0; k < FD; ++k)
            acc += (double)s_featT[k] * (double)weight1[(size_t)k * HD + tid];
        float v = (float)acc;
        s_tmp[tid] = v > 0.f ? v : 0.f;
    }
    __syncthreads();

    // tarfeat = tmp_emb @ weight2  [40]; wlabel/wsec into graph
    if (tid < LD) {
        double acc = 0.0;
        #pragma unroll 4
        for (int k = 0; k < HD; ++k)
            acc += (double)s_tmp[k] * (double)weight2[(size_t)k * LD + tid];
        s_graph[2*FD + tid]        = (float)acc;
        s_graph[2*FD + LD + tid]   = wlabel[tid];
        s_graph[2*FD + 2*LD + tid] = wsec[tid];
    }
    __syncthreads();

    // h1 = leaky_relu(graph @ W1 + b1)  [128]
    if (tid < HID1) {
        double acc = (double)b1[tid];
        #pragma unroll 4
        for (int k = 0; k < GD; ++k)
            acc += (double)s_graph[k] * (double)W1[(size_t)k * HID1 + tid];
        float v = (float)acc;
        s_h1[tid] = v >= 0.f ? v : 0.01f * v;
    }
    __syncthreads();

    // h2 = leaky_relu(h1 @ W2 + b2)  [512]
    {
        double acc = (double)b2[tid];
        #pragma unroll 4
        for (int k = 0; k < HID1; ++k)
            acc += (double)s_h1[k] * (double)W2[(size_t)k * HID2 + tid];
        float v = (float)acc;
        s_h2[tid] = v >= 0.f ? v : 0.01f * v;
    }
    __syncthreads();

    // add_feat = h2 @ W3 + b3  [512]  (kept in register, one per thread)
    float addv;
    {
        double acc = (double)b3[tid];
        #pragma unroll 4
        for (int k = 0; k < HID2; ++k)
            acc += (double)s_h2[k] * (double)W3[(size_t)k * FD + tid];
        addv = (float)acc;
    }
    s_mask[tid] = 0.f;
    __syncthreads();

    // ---- gumbel_topk: inj = sum of 50 masked softmaxes, temp 0.001 ----
    const int budget = feat_num[0];
    float inj = 0.f;
    for (int it = 0; it < budget; ++it) {
        const float m = addv - s_mask[tid];

        // block argmax: max value, FIRST (smallest) index on ties
        float v = m; int i = tid;
        #pragma unroll
        for (int off = 32; off >= 1; off >>= 1) {
            float ov = __shfl_down(v, off, 64);
            int   oi = __shfl_down(i, off, 64);
            if (ov > v || (ov == v && oi < i)) { v = ov; i = oi; }
        }
        if ((tid & 63) == 0) { s_redV[tid >> 6] = v; s_redI[tid >> 6] = i; }
        __syncthreads();
        if (tid == 0) {
            #pragma unroll
            for (int w = 1; w < 8; ++w)
                if (s_redV[w] > v || (s_redV[w] == v && s_redI[w] < i)) {
                    v = s_redV[w]; i = s_redI[w];
                }
            s_bcastV = v; s_bcastI = i;
        }
        __syncthreads();
        const float maxv = s_bcastV;
        if (tid == 0) s_mask[s_bcastI] = 9999.f;  // visible after sum barriers

        // softmax((logits - mask)/0.001) with current (pre-update) mask
        const float e = expf((m - maxv) * 1000.0f);  // masked -> exp(-1e7) = 0
        float s = e;
        #pragma unroll
        for (int off = 32; off >= 1; off >>= 1) s += __shfl_down(s, off, 64);
        if ((tid & 63) == 0) s_redV[tid >> 6] = s;
        __syncthreads();
        if (tid == 0) {
            float t = 0.f;
            #pragma unroll
            for (int w = 0; w < 8; ++w) t += s_redV[w];
            s_bcastV = t;
        }
        __syncthreads();
        inj += e / s_bcastV;
        // next iteration's s_redV write is gated by its own first barrier,
        // and s_mask write above is already 2 barriers old -> safe
    }

    // row N of new_feat, then output-1 (inj_feat) right after
    const size_t base = (size_t)NN * FD;
    out[base + tid]      = inj;
    out[base + FD + tid] = inj;
}

extern "C" void kernel_launch(void* const* d_in, const int* in_sizes, int n_in,
                              void* d_out, int out_size, void* d_ws, size_t ws_size,
                              hipStream_t stream) {
    (void)in_sizes; (void)n_in; (void)d_ws; (void)ws_size; (void)out_size;
    const int*   target    = (const int*)  d_in[0];
    const int*   sub_nodes = (const int*)  d_in[1];
    const float* feat      = (const float*)d_in[2];
    const float* node_emb  = (const float*)d_in[3];
    const float* wlabel    = (const float*)d_in[4];
    const float* wsec      = (const float*)d_in[5];
    const float* weight1   = (const float*)d_in[6];
    const float* weight2   = (const float*)d_in[7];
    const float* W1        = (const float*)d_in[8];
    const float* b1        = (const float*)d_in[9];
    const float* W2        = (const float*)d_in[10];
    const float* b2        = (const float*)d_in[11];
    const float* W3        = (const float*)d_in[12];
    const float* b3        = (const float*)d_in[13];
    const int*   feat_num  = (const int*)  d_in[14];
    float* out = (float*)d_out;

    dim3 grid(2048), block(512);
    hipLaunchKernelGGL(attrgen_fused, grid, block, 0, stream,
                       target, sub_nodes, feat, node_emb, wlabel, wsec,
                       weight1, weight2, W1, b1, W2, b2, W3, b3, feat_num, out);
}